// Round 7
// baseline (230.466 us; speedup 1.0000x reference)
//
#include <hip/hip_runtime.h>
#include <stdint.h>

typedef __attribute__((ext_vector_type(4))) float f32x4;
typedef __attribute__((ext_vector_type(8))) short short8;
typedef unsigned short u16;

#define NH 16
#define HD 64
#define SEQ 4096
#define BATCH 4
#define NROWS (BATCH * SEQ)      // 16384
#define DIMC 1024
#define QKVC 3072
#define SCALE 0.125f

__device__ __forceinline__ u16 f2bf(float f) {
  union { float f; uint32_t u; } v; v.f = f;
  uint32_t u = v.u;
  uint32_t r = (u + 0x7fffu + ((u >> 16) & 1u)) >> 16;
  return (u16)r;
}
__device__ __forceinline__ float bf2f(u16 h) {
  union { uint32_t u; float f; } v; v.u = ((uint32_t)h) << 16;
  return v.f;
}

// ---------------- fp32 -> bf16 elementwise convert (vectorized) ----------------
__global__ __launch_bounds__(256) void cvt_kernel(const float* __restrict__ in,
                                                  u16* __restrict__ out, int n4) {
  int i = blockIdx.x * 256 + threadIdx.x;
  if (i >= n4) return;
  float4 v = ((const float4*)in)[i];
  ushort4 o;
  o.x = f2bf(v.x); o.y = f2bf(v.y); o.z = f2bf(v.z); o.w = f2bf(v.w);
  ((ushort4*)out)[i] = o;
}

// ---------------- fp32 [R][C] -> bf16 [C][R] transpose ----------------
__global__ __launch_bounds__(256) void transpose_cvt(const float* __restrict__ in,
                                                     u16* __restrict__ out, int R, int C) {
  __shared__ float t[32][33];
  int nbx = C >> 5;
  int bx = blockIdx.x % nbx, by = blockIdx.x / nbx;
  int r0 = by << 5, c0 = bx << 5;
  int tid = threadIdx.x;
#pragma unroll
  for (int i = 0; i < 4; i++) {
    int id = i * 256 + tid; int lr = id >> 5, lc = id & 31;
    t[lr][lc] = in[(size_t)(r0 + lr) * C + (c0 + lc)];
  }
  __syncthreads();
#pragma unroll
  for (int i = 0; i < 4; i++) {
    int id = i * 256 + tid; int lr = id >> 5, lc = id & 31;
    out[(size_t)(c0 + lr) * R + (r0 + lc)] = f2bf(t[lc][lr]);
  }
}

// ---------------- bf16 GEMM: C[M,N] = A[M,K] * Bt[N,K]^T ----------------
// Exact m201 8-phase schedule. BM=BN=256, BK=64, 512 thr = 8 waves (2M x 4N),
// per-wave 128x64 (acc[8][4]). LDS 128 KiB = 2 dbuf x (A 256x64 + B 256x64).
// Per iter = 2 K-tiles (T0->buf0, T1->buf1), 8 phases; each phase:
//   {ds_read subtile | stage 1 half-tile | [lgkm(8) if 12 reads] | barrier |
//    lgkm(0) | setprio1 | 16 MFMA | setprio0 | barrier}
// counted vmcnt(4) at P4/P8 only (retires exactly the next tile's 8 loads).
// Staging slots: P1,P2->A(T1); P3,P4->B(T0+2); P5,P6->A(T0+2); P7,P8->B(T1+2).
// Every staged region is >=2 barriers past its last ds_read (liveness checked).
template <int OUT_BF16, int DO_SUMS>
__global__ __launch_bounds__(512, 2) void gemm_bt(const u16* __restrict__ A,
                                                  const u16* __restrict__ Bt,
                                                  void* __restrict__ Cv,
                                                  float* __restrict__ chk,
                                                  float* __restrict__ chv,
                                                  int M, int N, int K) {
  __shared__ __align__(16) u16 lds2[2][32768];   // per dbuf: A[0..16383], B[16384..32767]
  int nbx = N >> 8;
  int nwg = gridDim.x;
  int bid = blockIdx.x;
  int cpx = nwg >> 3;                       // grids are multiples of 8
  int swz = (bid & 7) * cpx + (bid >> 3);
  int bx = swz % nbx, by = swz / nbx;
  int tid = threadIdx.x, lane = tid & 63, wv = tid >> 6;
  int wr = wv >> 2, wc = wv & 3;            // wave grid 2 (M) x 4 (N)
  int lr = lane & 15, g = lane >> 4;
  int rx = lr & 7;
  int rsub = lane >> 3;                     // staging: row within 8-row unit
  int clog = (lane & 7) ^ rsub;             // staging: logical (global) chunk

  const u16* Ap = A + (size_t)(by * 256) * K;
  const u16* Bp = Bt + (size_t)(bx * 256) * K;

  f32x4 acc[8][4];
#pragma unroll
  for (int m = 0; m < 8; m++)
#pragma unroll
    for (int n = 0; n < 4; n++) acc[m][n] = (f32x4){0.f, 0.f, 0.f, 0.f};

  short8 a0[4][2], a1[4][2], b0[2][2], b1[2][2];

#define ISSUE_A(HALF, L, T) do {                                                \
    int ru_ = (HALF) * 128 + (L) * 64 + wv * 8;                                 \
    const u16* g_ = Ap + (size_t)(ru_ + rsub) * K + (T) * 64 + clog * 8;        \
    __builtin_amdgcn_global_load_lds(                                           \
        (const __attribute__((address_space(1))) uint32_t*)g_,                  \
        (__attribute__((address_space(3))) uint32_t*)&lds2[(T) & 1][ru_ * 64],  \
        16, 0, 0);                                                              \
  } while (0)

#define ISSUE_B(HALF, L, T) do {                                                \
    int ru_ = (HALF) * 128 + (L) * 64 + wv * 8;                                 \
    const u16* g_ = Bp + (size_t)(ru_ + rsub) * K + (T) * 64 + clog * 8;        \
    __builtin_amdgcn_global_load_lds(                                           \
        (const __attribute__((address_space(1))) uint32_t*)g_,                  \
        (__attribute__((address_space(3)))                                      \
             uint32_t*)&lds2[(T) & 1][16384 + ru_ * 64],                        \
        16, 0, 0);                                                              \
  } while (0)

#define LDA(DST, MH, T) do {                                                    \
    _Pragma("unroll")                                                           \
    for (int m2 = 0; m2 < 4; m2++) {                                            \
      int row_ = wr * 128 + ((MH) * 4 + m2) * 16 + lr;                          \
      const u16* bp_ = &lds2[(T) & 1][row_ * 64];                               \
      _Pragma("unroll")                                                         \
      for (int s = 0; s < 2; s++)                                               \
        DST[m2][s] = *(const short8*)(bp_ + (((s * 4 + g) ^ rx) << 3));         \
    }                                                                           \
  } while (0)

#define LDB(DST, NHh, T) do {                                                   \
    _Pragma("unroll")                                                           \
    for (int n2 = 0; n2 < 2; n2++) {                                            \
      int row_ = wc * 64 + ((NHh) * 2 + n2) * 16 + lr;                          \
      const u16* bp_ = &lds2[(T) & 1][16384 + row_ * 64];                       \
      _Pragma("unroll")                                                         \
      for (int s = 0; s < 2; s++)                                               \
        DST[n2][s] = *(const short8*)(bp_ + (((s * 4 + g) ^ rx) << 3));         \
    }                                                                           \
  } while (0)

#define MFMA_Q(MH, NHh, AA, BB) do {                                            \
    _Pragma("unroll")                                                           \
    for (int s = 0; s < 2; s++)                                                 \
      _Pragma("unroll")                                                         \
      for (int m2 = 0; m2 < 4; m2++)                                            \
        _Pragma("unroll")                                                       \
        for (int n2 = 0; n2 < 2; n2++)                                          \
          acc[(MH) * 4 + m2][(NHh) * 2 + n2] =                                  \
              __builtin_amdgcn_mfma_f32_16x16x32_bf16(                          \
                  AA[m2][s], BB[n2][s], acc[(MH) * 4 + m2][(NHh) * 2 + n2],     \
                  0, 0, 0);                                                     \
  } while (0)

#define PH_PRE(NREADS)                                                          \
    __builtin_amdgcn_sched_barrier(0);                                          \
    if (NREADS >= 12) { asm volatile("s_waitcnt lgkmcnt(8)" ::: "memory"); }    \
    __builtin_amdgcn_s_barrier();                                               \
    asm volatile("s_waitcnt lgkmcnt(0)" ::: "memory");                          \
    __builtin_amdgcn_sched_barrier(0);                                          \
    __builtin_amdgcn_s_setprio(1)

#define PH_POST                                                                 \
    __builtin_amdgcn_s_setprio(0);                                              \
    __builtin_amdgcn_sched_barrier(0);                                          \
    __builtin_amdgcn_s_barrier()

  int NT = K >> 6;
  // prologue: tile0 A+B, tile1 B; retire tile0 (12 outstanding -> vmcnt 4)
  ISSUE_A(0, 0, 0); ISSUE_A(0, 1, 0); ISSUE_A(1, 0, 0); ISSUE_A(1, 1, 0);
  ISSUE_B(0, 0, 0); ISSUE_B(0, 1, 0); ISSUE_B(1, 0, 0); ISSUE_B(1, 1, 0);
  ISSUE_B(0, 0, 1); ISSUE_B(0, 1, 1); ISSUE_B(1, 0, 1); ISSUE_B(1, 1, 1);
  __builtin_amdgcn_sched_barrier(0);
  asm volatile("s_waitcnt vmcnt(4)" ::: "memory");
  __builtin_amdgcn_sched_barrier(0);
  __builtin_amdgcn_s_barrier();

  int NI = NT >> 1;
  for (int i = 0; i < NI; i++) {
    int T0 = 2 * i, T1 = 2 * i + 1;
    int st0 = (T0 + 2 < NT), st1 = (T1 + 2 < NT);
    // ================= K-tile T0 (buf0) =================
    // P1: rd a0,b0 | stage Ah0(T1) | Q00
    LDA(a0, 0, T0); LDB(b0, 0, T0);
    ISSUE_A(0, 0, T1); ISSUE_A(0, 1, T1);
    PH_PRE(12);
    MFMA_Q(0, 0, a0, b0);
    PH_POST;
    // P2: rd b1 | stage Ah1(T1) | Q01
    LDB(b1, 1, T0);
    ISSUE_A(1, 0, T1); ISSUE_A(1, 1, T1);
    PH_PRE(4);
    MFMA_Q(0, 1, a0, b1);
    PH_POST;
    // P3: rd a1 | stage Bh0(T0+2) | Q11
    LDA(a1, 1, T0);
    if (st0) { ISSUE_B(0, 0, T0 + 2); ISSUE_B(0, 1, T0 + 2); }
    PH_PRE(8);
    MFMA_Q(1, 1, a1, b1);
    PH_POST;
    // P4: stage Bh1(T0+2) | vmcnt(4) | Q10
    if (st0) { ISSUE_B(1, 0, T0 + 2); ISSUE_B(1, 1, T0 + 2); }
    __builtin_amdgcn_sched_barrier(0);
    if (st0) asm volatile("s_waitcnt vmcnt(4)" ::: "memory");
    else     asm volatile("s_waitcnt vmcnt(0)" ::: "memory");
    __builtin_amdgcn_sched_barrier(0);
    __builtin_amdgcn_s_barrier();
    __builtin_amdgcn_s_setprio(1);
    MFMA_Q(1, 0, a1, b0);
    PH_POST;
    // ================= K-tile T1 (buf1) =================
    // P5: rd a0,b0 | stage Ah0(T0+2) | Q00
    LDA(a0, 0, T1); LDB(b0, 0, T1);
    if (st0) { ISSUE_A(0, 0, T0 + 2); ISSUE_A(0, 1, T0 + 2); }
    PH_PRE(12);
    MFMA_Q(0, 0, a0, b0);
    PH_POST;
    // P6: rd b1 | stage Ah1(T0+2) | Q01
    LDB(b1, 1, T1);
    if (st0) { ISSUE_A(1, 0, T0 + 2); ISSUE_A(1, 1, T0 + 2); }
    PH_PRE(4);
    MFMA_Q(0, 1, a0, b1);
    PH_POST;
    // P7: rd a1 | stage Bh0(T1+2) | Q11
    LDA(a1, 1, T1);
    if (st1) { ISSUE_B(0, 0, T1 + 2); ISSUE_B(0, 1, T1 + 2); }
    PH_PRE(8);
    MFMA_Q(1, 1, a1, b1);
    PH_POST;
    // P8: stage Bh1(T1+2) | vmcnt(4) | Q10
    if (st1) { ISSUE_B(1, 0, T1 + 2); ISSUE_B(1, 1, T1 + 2); }
    __builtin_amdgcn_sched_barrier(0);
    if (st1) asm volatile("s_waitcnt vmcnt(4)" ::: "memory");
    else     asm volatile("s_waitcnt vmcnt(0)" ::: "memory");
    __builtin_amdgcn_sched_barrier(0);
    __builtin_amdgcn_s_barrier();
    __builtin_amdgcn_s_setprio(1);
    MFMA_Q(1, 0, a1, b0);
    PH_POST;
  }

#undef ISSUE_A
#undef ISSUE_B
#undef LDA
#undef LDB
#undef MFMA_Q
#undef PH_PRE
#undef PH_POST

  int rb = by * 256 + wr * 128, cb = bx * 256 + wc * 64;

  if (DO_SUMS && cb >= 1024) {
    // fused chunk means: wave owns chunks (wr*2+mh); sum fp32 acc over rows.
#pragma unroll
    for (int mh = 0; mh < 2; mh++)
#pragma unroll
      for (int n = 0; n < 4; n++) {
        float sum = 0.f;
#pragma unroll
        for (int m = mh * 4; m < mh * 4 + 4; m++)
#pragma unroll
          for (int r = 0; r < 4; r++) sum += acc[m][n][r];
        sum += __shfl_xor(sum, 16);
        sum += __shfl_xor(sum, 32);
        if (g == 0) {
          int grb = rb + mh * 64;
          int b = grb >> 12, c = (grb >> 6) & 63;
          int cg = cb + n * 16 + lr;
          int col = cg & 1023;
          int h = col >> 6, d = col & 63;
          float* dst = (cg < 2048) ? chk : chv;
          dst[(((size_t)(b * 16 + h)) * 64 + c) * 64 + d] = sum * 0.015625f;
        }
      }
  }

#pragma unroll
  for (int m = 0; m < 8; m++)
#pragma unroll
    for (int n = 0; n < 4; n++)
#pragma unroll
      for (int r = 0; r < 4; r++) {
        int rg = rb + m * 16 + g * 4 + r;
        int cg = cb + n * 16 + lr;
        float v = acc[m][n][r];
        if (OUT_BF16)
          ((u16*)Cv)[(size_t)rg * N + cg] = f2bf(v);
        else
          ((float*)Cv)[(size_t)rg * N + cg] = v;
      }
}

// ---------------- exclusive cumsum over chunks ----------------
__global__ void cumsum_excl(const float* __restrict__ ck, const float* __restrict__ cv,
                            float* __restrict__ cuk, float* __restrict__ cuv) {
  int bh = blockIdx.x;
  int d = threadIdx.x;
  float ak = 0.f, av = 0.f;
  for (int c = 0; c < 64; c++) {
    size_t i = ((size_t)bh * 64 + c) * 64 + d;
    cuk[i] = ak; cuv[i] = av;
    ak += ck[i]; av += cv[i];
  }
}

// ---------------- per-chunk attention + cross term ----------------
__global__ __launch_bounds__(256) void attn_kernel(const u16* __restrict__ qkv,
                                                   const float* __restrict__ cuk,
                                                   const float* __restrict__ cuv,
                                                   u16* __restrict__ out) {
  int blk = blockIdx.x;
  int c = blk & 63, h = (blk >> 6) & 15, b = blk >> 10;
  int row0 = b * SEQ + c * 64;
  __shared__ u16 q_s[64][80];
  __shared__ u16 k_s[64][80];
  __shared__ u16 vt_s[64][80];   // V transposed: vt_s[d][krow]
  __shared__ u16 p_s[64][80];
  __shared__ u16 ck_s[64];
  __shared__ float cv_s[64];
  int tid = threadIdx.x;
  {
    int r = tid >> 2, qt = tid & 3;
    const u16* rp = qkv + (size_t)(row0 + r) * QKVC + h * 64 + qt * 16;
    uint4 q0 = *(const uint4*)rp;          uint4 q1 = *(const uint4*)(rp + 8);
    uint4 k0 = *(const uint4*)(rp + 1024); uint4 k1 = *(const uint4*)(rp + 1032);
    uint4 v0 = *(const uint4*)(rp + 2048); uint4 v1 = *(const uint4*)(rp + 2056);
    *(uint4*)&q_s[r][qt * 16] = q0;     *(uint4*)&q_s[r][qt * 16 + 8] = q1;
    *(uint4*)&k_s[r][qt * 16] = k0;     *(uint4*)&k_s[r][qt * 16 + 8] = k1;
    const u16* vv0 = (const u16*)&v0;   const u16* vv1 = (const u16*)&v1;
#pragma unroll
    for (int j = 0; j < 8; j++) vt_s[qt * 16 + j][r] = vv0[j];
#pragma unroll
    for (int j = 0; j < 8; j++) vt_s[qt * 16 + 8 + j][r] = vv1[j];
    if (tid < 64) {
      ck_s[tid] = f2bf(cuk[(size_t)blk * 64 + tid]);
      cv_s[tid] = cuv[(size_t)blk * 64 + tid];
    }
  }
  __syncthreads();

  int lane = tid & 63, w = tid >> 6;
  int lr = lane & 15, g = lane >> 4;
  f32x4 accS[4];
#pragma unroll
  for (int n = 0; n < 4; n++) accS[n] = (f32x4){0.f, 0.f, 0.f, 0.f};
  f32x4 accC = (f32x4){0.f, 0.f, 0.f, 0.f};
  short8 zf = (short8){0, 0, 0, 0, 0, 0, 0, 0};
#pragma unroll
  for (int kt = 0; kt < 2; kt++) {
    int lk = kt * 32 + g * 8;
    short8 af = *(const short8*)&q_s[w * 16 + lr][lk];
    short8 cf = (lr == 0) ? *(const short8*)&ck_s[lk] : zf;
    accC = __builtin_amdgcn_mfma_f32_16x16x32_bf16(af, cf, accC, 0, 0, 0);
#pragma unroll
    for (int n = 0; n < 4; n++) {
      short8 bf = *(const short8*)&k_s[n * 16 + lr][lk];
      accS[n] = __builtin_amdgcn_mfma_f32_16x16x32_bf16(af, bf, accS[n], 0, 0, 0);
    }
  }
  float crossv[4];
#pragma unroll
  for (int r4 = 0; r4 < 4; r4++) {
    int row = w * 16 + g * 4 + r4;
    float x[4];
    float mx = -3.4e38f;
#pragma unroll
    for (int n = 0; n < 4; n++) {
      int col = n * 16 + lr;
      x[n] = ((col & 63) > (row & 63)) ? -65000.0f : accS[n][r4] * SCALE;
      mx = fmaxf(mx, x[n]);
    }
    mx = fmaxf(mx, __shfl_xor(mx, 1));
    mx = fmaxf(mx, __shfl_xor(mx, 2));
    mx = fmaxf(mx, __shfl_xor(mx, 4));
    mx = fmaxf(mx, __shfl_xor(mx, 8));
    float p[4], sum = 0.f;
#pragma unroll
    for (int n = 0; n < 4; n++) { p[n] = __expf(x[n] - mx); sum += p[n]; }
    sum += __shfl_xor(sum, 1);
    sum += __shfl_xor(sum, 2);
    sum += __shfl_xor(sum, 4);
    sum += __shfl_xor(sum, 8);
    float inv = 1.0f / sum;
#pragma unroll
    for (int n = 0; n < 4; n++) p_s[row][n * 16 + lr] = f2bf(p[n] * inv);
    float sg = 1.0f / (1.0f + __expf(-accC[r4] * SCALE));
    crossv[r4] = __shfl(sg, (lane & 48));
  }
  __syncthreads();
  f32x4 accO[4];
#pragma unroll
  for (int n = 0; n < 4; n++) accO[n] = (f32x4){0.f, 0.f, 0.f, 0.f};
#pragma unroll
  for (int kt = 0; kt < 2; kt++) {
    int lk = kt * 32 + g * 8;
    short8 pf = *(const short8*)&p_s[w * 16 + lr][lk];
#pragma unroll
    for (int n = 0; n < 4; n++) {
      short8 vf = *(const short8*)&vt_s[n * 16 + lr][lk];
      accO[n] = __builtin_amdgcn_mfma_f32_16x16x32_bf16(pf, vf, accO[n], 0, 0, 0);
    }
  }
#pragma unroll
  for (int n = 0; n < 4; n++)
#pragma unroll
    for (int r4 = 0; r4 < 4; r4++) {
      int row = w * 16 + g * 4 + r4;
      int col = n * 16 + lr;
      float v = accO[n][r4] + crossv[r4] * cv_s[col] * 0.5f;
      out[(size_t)(row0 + row) * DIMC + h * 64 + col] = f2bf(v);
    }
}

extern "C" void kernel_launch(void* const* d_in, const int* in_sizes, int n_in,
                              void* d_out, int out_size, void* d_ws, size_t ws_size,
                              hipStream_t stream) {
  const float* x = (const float*)d_in[0];
  const float* Wqkv = (const float*)d_in[1];
  const float* Wout = (const float*)d_in[2];
  char* ws = (char*)d_ws;
  size_t off = 0;
  auto alloc = [&](size_t b) {
    void* p = ws + off;
    off += (b + 255) & ~(size_t)255;
    return p;
  };
  u16* xb = (u16*)alloc((size_t)NROWS * DIMC * 2);        // 32MB, reused as attnb
  u16* wqt = (u16*)alloc((size_t)QKVC * DIMC * 2);        // 6MB
  u16* wot = (u16*)alloc((size_t)DIMC * DIMC * 2);        // 2MB
  u16* qkvb = (u16*)alloc((size_t)NROWS * QKVC * 2);      // 96MB
  float* chk = (float*)alloc((size_t)4096 * 64 * 4);
  float* chv = (float*)alloc((size_t)4096 * 64 * 4);
  float* cuk = (float*)alloc((size_t)4096 * 64 * 4);
  float* cuv = (float*)alloc((size_t)4096 * 64 * 4);
  u16* attnb = xb;

  cvt_kernel<<<16384, 256, 0, stream>>>(x, xb, NROWS * DIMC / 4);
  transpose_cvt<<<3072, 256, 0, stream>>>(Wqkv, wqt, DIMC, QKVC);
  transpose_cvt<<<1024, 256, 0, stream>>>(Wout, wot, DIMC, DIMC);
  gemm_bt<1, 1><<<768, 512, 0, stream>>>(xb, wqt, qkvb, chk, chv, NROWS, QKVC, DIMC);
  cumsum_excl<<<64, 64, 0, stream>>>(chk, chv, cuk, cuv);
  attn_kernel<<<4096, 256, 0, stream>>>(qkvb, cuk, cuv, attnb);
  gemm_bt<0, 0><<<256, 512, 0, stream>>>(attnb, wot, d_out, nullptr, nullptr,
                                         NROWS, DIMC, DIMC);
}

// Round 8
// 230.268 us; speedup vs baseline: 1.0009x; 1.0009x over previous
//
#include <hip/hip_runtime.h>
#include <stdint.h>

typedef __attribute__((ext_vector_type(4))) float f32x4;
typedef __attribute__((ext_vector_type(8))) short short8;
typedef unsigned short u16;

#define NH 16
#define HD 64
#define SEQ 4096
#define BATCH 4
#define NROWS (BATCH * SEQ)      // 16384
#define DIMC 1024
#define QKVC 3072
#define SCALE 0.125f

__device__ __forceinline__ u16 f2bf(float f) {
  union { float f; uint32_t u; } v; v.f = f;
  uint32_t u = v.u;
  uint32_t r = (u + 0x7fffu + ((u >> 16) & 1u)) >> 16;
  return (u16)r;
}
__device__ __forceinline__ float bf2f(u16 h) {
  union { uint32_t u; float f; } v; v.u = ((uint32_t)h) << 16;
  return v.f;
}

// ---------------- fp32 -> bf16 elementwise convert (vectorized) ----------------
__global__ __launch_bounds__(256) void cvt_kernel(const float* __restrict__ in,
                                                  u16* __restrict__ out, int n4) {
  int i = blockIdx.x * 256 + threadIdx.x;
  if (i >= n4) return;
  float4 v = ((const float4*)in)[i];
  ushort4 o;
  o.x = f2bf(v.x); o.y = f2bf(v.y); o.z = f2bf(v.z); o.w = f2bf(v.w);
  ((ushort4*)out)[i] = o;
}

// ---------------- fp32 [R][C] -> bf16 [C][R] transpose ----------------
__global__ __launch_bounds__(256) void transpose_cvt(const float* __restrict__ in,
                                                     u16* __restrict__ out, int R, int C) {
  __shared__ float t[32][33];
  int nbx = C >> 5;
  int bx = blockIdx.x % nbx, by = blockIdx.x / nbx;
  int r0 = by << 5, c0 = bx << 5;
  int tid = threadIdx.x;
#pragma unroll
  for (int i = 0; i < 4; i++) {
    int id = i * 256 + tid; int lr = id >> 5, lc = id & 31;
    t[lr][lc] = in[(size_t)(r0 + lr) * C + (c0 + lc)];
  }
  __syncthreads();
#pragma unroll
  for (int i = 0; i < 4; i++) {
    int id = i * 256 + tid; int lr = id >> 5, lc = id & 31;
    out[(size_t)(c0 + lr) * R + (r0 + lc)] = f2bf(t[lc][lr]);
  }
}

// ---------------- bf16 GEMM: C[M,N] = A[M,K] * Bt[N,K]^T ----------------
// m201 8-phase schedule. BM=BN=256, BK=64, 512 thr = 8 waves (2M x 4N),
// per-wave 128x64 (acc[8][4]). LDS 128 KiB = 2 dbuf x (A 256x64 + B 256x64).
// __launch_bounds__(512,1): LDS already caps at 1 block/CU (2 waves/SIMD);
// the (512,2) cap of 128 VGPR forced fragment spills (r7: WRITE_SIZE +17MB).
template <int OUT_BF16, int DO_SUMS>
__global__ __launch_bounds__(512, 1) void gemm_bt(const u16* __restrict__ A,
                                                  const u16* __restrict__ Bt,
                                                  void* __restrict__ Cv,
                                                  float* __restrict__ chk,
                                                  float* __restrict__ chv,
                                                  int M, int N, int K) {
  __shared__ __align__(16) u16 lds2[2][32768];   // per dbuf: A[0..16383], B[16384..32767]
  int nbx = N >> 8;
  int nwg = gridDim.x;
  int bid = blockIdx.x;
  int cpx = nwg >> 3;                       // grids are multiples of 8
  int swz = (bid & 7) * cpx + (bid >> 3);
  int bx = swz % nbx, by = swz / nbx;
  int tid = threadIdx.x, lane = tid & 63, wv = tid >> 6;
  int wr = wv >> 2, wc = wv & 3;            // wave grid 2 (M) x 4 (N)
  int lr = lane & 15, g = lane >> 4;
  int rx = lr & 7;
  int rsub = lane >> 3;                     // staging: row within 8-row unit
  int clog = (lane & 7) ^ rsub;             // staging: logical (global) chunk

  const u16* Ap = A + (size_t)(by * 256) * K;
  const u16* Bp = Bt + (size_t)(bx * 256) * K;

  f32x4 acc[8][4];
#pragma unroll
  for (int m = 0; m < 8; m++)
#pragma unroll
    for (int n = 0; n < 4; n++) acc[m][n] = (f32x4){0.f, 0.f, 0.f, 0.f};

  short8 a0[4][2], a1[4][2], b0[2][2], b1[2][2];

#define ISSUE_A(HALF, L, T) do {                                                \
    int ru_ = (HALF) * 128 + (L) * 64 + wv * 8;                                 \
    const u16* g_ = Ap + (size_t)(ru_ + rsub) * K + (T) * 64 + clog * 8;        \
    __builtin_amdgcn_global_load_lds(                                           \
        (const __attribute__((address_space(1))) uint32_t*)g_,                  \
        (__attribute__((address_space(3))) uint32_t*)&lds2[(T) & 1][ru_ * 64],  \
        16, 0, 0);                                                              \
  } while (0)

#define ISSUE_B(HALF, L, T) do {                                                \
    int ru_ = (HALF) * 128 + (L) * 64 + wv * 8;                                 \
    const u16* g_ = Bp + (size_t)(ru_ + rsub) * K + (T) * 64 + clog * 8;        \
    __builtin_amdgcn_global_load_lds(                                           \
        (const __attribute__((address_space(1))) uint32_t*)g_,                  \
        (__attribute__((address_space(3)))                                      \
             uint32_t*)&lds2[(T) & 1][16384 + ru_ * 64],                        \
        16, 0, 0);                                                              \
  } while (0)

#define LDA(DST, MH, T) do {                                                    \
    _Pragma("unroll")                                                           \
    for (int m2 = 0; m2 < 4; m2++) {                                            \
      int row_ = wr * 128 + ((MH) * 4 + m2) * 16 + lr;                          \
      const u16* bp_ = &lds2[(T) & 1][row_ * 64];                               \
      _Pragma("unroll")                                                         \
      for (int s = 0; s < 2; s++)                                               \
        DST[m2][s] = *(const short8*)(bp_ + (((s * 4 + g) ^ rx) << 3));         \
    }                                                                           \
  } while (0)

#define LDB(DST, NHh, T) do {                                                   \
    _Pragma("unroll")                                                           \
    for (int n2 = 0; n2 < 2; n2++) {                                            \
      int row_ = wc * 64 + ((NHh) * 2 + n2) * 16 + lr;                          \
      const u16* bp_ = &lds2[(T) & 1][16384 + row_ * 64];                       \
      _Pragma("unroll")                                                         \
      for (int s = 0; s < 2; s++)                                               \
        DST[n2][s] = *(const short8*)(bp_ + (((s * 4 + g) ^ rx) << 3));         \
    }                                                                           \
  } while (0)

#define MFMA_Q(MH, NHh, AA, BB) do {                                            \
    _Pragma("unroll")                                                           \
    for (int s = 0; s < 2; s++)                                                 \
      _Pragma("unroll")                                                         \
      for (int m2 = 0; m2 < 4; m2++)                                            \
        _Pragma("unroll")                                                       \
        for (int n2 = 0; n2 < 2; n2++)                                          \
          acc[(MH) * 4 + m2][(NHh) * 2 + n2] =                                  \
              __builtin_amdgcn_mfma_f32_16x16x32_bf16(                          \
                  AA[m2][s], BB[n2][s], acc[(MH) * 4 + m2][(NHh) * 2 + n2],     \
                  0, 0, 0);                                                     \
  } while (0)

#define PH_PRE(NREADS)                                                          \
    __builtin_amdgcn_sched_barrier(0);                                          \
    if (NREADS >= 12) { asm volatile("s_waitcnt lgkmcnt(8)" ::: "memory"); }    \
    __builtin_amdgcn_s_barrier();                                               \
    asm volatile("s_waitcnt lgkmcnt(0)" ::: "memory");                          \
    __builtin_amdgcn_sched_barrier(0);                                          \
    __builtin_amdgcn_s_setprio(1)

#define PH_POST                                                                 \
    __builtin_amdgcn_s_setprio(0);                                              \
    __builtin_amdgcn_sched_barrier(0);                                          \
    __builtin_amdgcn_s_barrier()

  int NT = K >> 6;
  // prologue: tile0 A+B, tile1 B; retire tile0 (12 outstanding -> vmcnt 4)
  ISSUE_A(0, 0, 0); ISSUE_A(0, 1, 0); ISSUE_A(1, 0, 0); ISSUE_A(1, 1, 0);
  ISSUE_B(0, 0, 0); ISSUE_B(0, 1, 0); ISSUE_B(1, 0, 0); ISSUE_B(1, 1, 0);
  ISSUE_B(0, 0, 1); ISSUE_B(0, 1, 1); ISSUE_B(1, 0, 1); ISSUE_B(1, 1, 1);
  __builtin_amdgcn_sched_barrier(0);
  asm volatile("s_waitcnt vmcnt(4)" ::: "memory");
  __builtin_amdgcn_sched_barrier(0);
  __builtin_amdgcn_s_barrier();

  int NI = NT >> 1;
  for (int i = 0; i < NI; i++) {
    int T0 = 2 * i, T1 = 2 * i + 1;
    int st0 = (T0 + 2 < NT), st1 = (T1 + 2 < NT);
    // ================= K-tile T0 (buf0) =================
    // P1: rd a0,b0 | stage Ah0(T1) | Q00
    LDA(a0, 0, T0); LDB(b0, 0, T0);
    ISSUE_A(0, 0, T1); ISSUE_A(0, 1, T1);
    PH_PRE(12);
    MFMA_Q(0, 0, a0, b0);
    PH_POST;
    // P2: rd b1 | stage Ah1(T1) | Q01
    LDB(b1, 1, T0);
    ISSUE_A(1, 0, T1); ISSUE_A(1, 1, T1);
    PH_PRE(4);
    MFMA_Q(0, 1, a0, b1);
    PH_POST;
    // P3: rd a1 | stage Bh0(T0+2) | Q11
    LDA(a1, 1, T0);
    if (st0) { ISSUE_B(0, 0, T0 + 2); ISSUE_B(0, 1, T0 + 2); }
    PH_PRE(8);
    MFMA_Q(1, 1, a1, b1);
    PH_POST;
    // P4: stage Bh1(T0+2) | vmcnt(4) | Q10
    if (st0) { ISSUE_B(1, 0, T0 + 2); ISSUE_B(1, 1, T0 + 2); }
    __builtin_amdgcn_sched_barrier(0);
    if (st0) asm volatile("s_waitcnt vmcnt(4)" ::: "memory");
    else     asm volatile("s_waitcnt vmcnt(0)" ::: "memory");
    __builtin_amdgcn_sched_barrier(0);
    __builtin_amdgcn_s_barrier();
    __builtin_amdgcn_s_setprio(1);
    MFMA_Q(1, 0, a1, b0);
    PH_POST;
    // ================= K-tile T1 (buf1) =================
    // P5: rd a0,b0 | stage Ah0(T0+2) | Q00
    LDA(a0, 0, T1); LDB(b0, 0, T1);
    if (st0) { ISSUE_A(0, 0, T0 + 2); ISSUE_A(0, 1, T0 + 2); }
    PH_PRE(12);
    MFMA_Q(0, 0, a0, b0);
    PH_POST;
    // P6: rd b1 | stage Ah1(T0+2) | Q01
    LDB(b1, 1, T1);
    if (st0) { ISSUE_A(1, 0, T0 + 2); ISSUE_A(1, 1, T0 + 2); }
    PH_PRE(4);
    MFMA_Q(0, 1, a0, b1);
    PH_POST;
    // P7: rd a1 | stage Bh0(T1+2) | Q11
    LDA(a1, 1, T1);
    if (st1) { ISSUE_B(0, 0, T1 + 2); ISSUE_B(0, 1, T1 + 2); }
    PH_PRE(8);
    MFMA_Q(1, 1, a1, b1);
    PH_POST;
    // P8: stage Bh1(T1+2) | vmcnt(4) | Q10
    if (st1) { ISSUE_B(1, 0, T1 + 2); ISSUE_B(1, 1, T1 + 2); }
    __builtin_amdgcn_sched_barrier(0);
    if (st1) asm volatile("s_waitcnt vmcnt(4)" ::: "memory");
    else     asm volatile("s_waitcnt vmcnt(0)" ::: "memory");
    __builtin_amdgcn_sched_barrier(0);
    __builtin_amdgcn_s_barrier();
    __builtin_amdgcn_s_setprio(1);
    MFMA_Q(1, 0, a1, b0);
    PH_POST;
  }

#undef ISSUE_A
#undef ISSUE_B
#undef LDA
#undef LDB
#undef MFMA_Q
#undef PH_PRE
#undef PH_POST

  int rb = by * 256 + wr * 128, cb = bx * 256 + wc * 64;

  if (DO_SUMS && cb >= 1024) {
    // fused chunk means: wave owns chunks (wr*2+mh); sum fp32 acc over rows.
#pragma unroll
    for (int mh = 0; mh < 2; mh++)
#pragma unroll
      for (int n = 0; n < 4; n++) {
        float sum = 0.f;
#pragma unroll
        for (int m = mh * 4; m < mh * 4 + 4; m++)
#pragma unroll
          for (int r = 0; r < 4; r++) sum += acc[m][n][r];
        sum += __shfl_xor(sum, 16);
        sum += __shfl_xor(sum, 32);
        if (g == 0) {
          int grb = rb + mh * 64;
          int b = grb >> 12, c = (grb >> 6) & 63;
          int cg = cb + n * 16 + lr;
          int col = cg & 1023;
          int h = col >> 6, d = col & 63;
          float* dst = (cg < 2048) ? chk : chv;
          dst[(((size_t)(b * 16 + h)) * 64 + c) * 64 + d] = sum * 0.015625f;
        }
      }
  }

#pragma unroll
  for (int m = 0; m < 8; m++)
#pragma unroll
    for (int n = 0; n < 4; n++)
#pragma unroll
      for (int r = 0; r < 4; r++) {
        int rg = rb + m * 16 + g * 4 + r;
        int cg = cb + n * 16 + lr;
        float v = acc[m][n][r];
        if (OUT_BF16)
          ((u16*)Cv)[(size_t)rg * N + cg] = f2bf(v);
        else
          ((float*)Cv)[(size_t)rg * N + cg] = v;
      }
}

// ---------------- exclusive cumsum over chunks ----------------
__global__ void cumsum_excl(const float* __restrict__ ck, const float* __restrict__ cv,
                            float* __restrict__ cuk, float* __restrict__ cuv) {
  int bh = blockIdx.x;
  int d = threadIdx.x;
  float ak = 0.f, av = 0.f;
  for (int c = 0; c < 64; c++) {
    size_t i = ((size_t)bh * 64 + c) * 64 + d;
    cuk[i] = ak; cuv[i] = av;
    ak += ck[i]; av += cv[i];
  }
}

// ---------------- per-chunk attention + cross term ----------------
__global__ __launch_bounds__(256) void attn_kernel(const u16* __restrict__ qkv,
                                                   const float* __restrict__ cuk,
                                                   const float* __restrict__ cuv,
                                                   u16* __restrict__ out) {
  int blk = blockIdx.x;
  int c = blk & 63, h = (blk >> 6) & 15, b = blk >> 10;
  int row0 = b * SEQ + c * 64;
  __shared__ u16 q_s[64][80];
  __shared__ u16 k_s[64][80];
  __shared__ u16 vt_s[64][80];   // V transposed: vt_s[d][krow]
  __shared__ u16 p_s[64][80];
  __shared__ u16 ck_s[64];
  __shared__ float cv_s[64];
  int tid = threadIdx.x;
  {
    int r = tid >> 2, qt = tid & 3;
    const u16* rp = qkv + (size_t)(row0 + r) * QKVC + h * 64 + qt * 16;
    uint4 q0 = *(const uint4*)rp;          uint4 q1 = *(const uint4*)(rp + 8);
    uint4 k0 = *(const uint4*)(rp + 1024); uint4 k1 = *(const uint4*)(rp + 1032);
    uint4 v0 = *(const uint4*)(rp + 2048); uint4 v1 = *(const uint4*)(rp + 2056);
    *(uint4*)&q_s[r][qt * 16] = q0;     *(uint4*)&q_s[r][qt * 16 + 8] = q1;
    *(uint4*)&k_s[r][qt * 16] = k0;     *(uint4*)&k_s[r][qt * 16 + 8] = k1;
    const u16* vv0 = (const u16*)&v0;   const u16* vv1 = (const u16*)&v1;
#pragma unroll
    for (int j = 0; j < 8; j++) vt_s[qt * 16 + j][r] = vv0[j];
#pragma unroll
    for (int j = 0; j < 8; j++) vt_s[qt * 16 + 8 + j][r] = vv1[j];
    if (tid < 64) {
      ck_s[tid] = f2bf(cuk[(size_t)blk * 64 + tid]);
      cv_s[tid] = cuv[(size_t)blk * 64 + tid];
    }
  }
  __syncthreads();

  int lane = tid & 63, w = tid >> 6;
  int lr = lane & 15, g = lane >> 4;
  f32x4 accS[4];
#pragma unroll
  for (int n = 0; n < 4; n++) accS[n] = (f32x4){0.f, 0.f, 0.f, 0.f};
  f32x4 accC = (f32x4){0.f, 0.f, 0.f, 0.f};
  short8 zf = (short8){0, 0, 0, 0, 0, 0, 0, 0};
#pragma unroll
  for (int kt = 0; kt < 2; kt++) {
    int lk = kt * 32 + g * 8;
    short8 af = *(const short8*)&q_s[w * 16 + lr][lk];
    short8 cf = (lr == 0) ? *(const short8*)&ck_s[lk] : zf;
    accC = __builtin_amdgcn_mfma_f32_16x16x32_bf16(af, cf, accC, 0, 0, 0);
#pragma unroll
    for (int n = 0; n < 4; n++) {
      short8 bf = *(const short8*)&k_s[n * 16 + lr][lk];
      accS[n] = __builtin_amdgcn_mfma_f32_16x16x32_bf16(af, bf, accS[n], 0, 0, 0);
    }
  }
  float crossv[4];
#pragma unroll
  for (int r4 = 0; r4 < 4; r4++) {
    int row = w * 16 + g * 4 + r4;
    float x[4];
    float mx = -3.4e38f;
#pragma unroll
    for (int n = 0; n < 4; n++) {
      int col = n * 16 + lr;
      x[n] = ((col & 63) > (row & 63)) ? -65000.0f : accS[n][r4] * SCALE;
      mx = fmaxf(mx, x[n]);
    }
    mx = fmaxf(mx, __shfl_xor(mx, 1));
    mx = fmaxf(mx, __shfl_xor(mx, 2));
    mx = fmaxf(mx, __shfl_xor(mx, 4));
    mx = fmaxf(mx, __shfl_xor(mx, 8));
    float p[4], sum = 0.f;
#pragma unroll
    for (int n = 0; n < 4; n++) { p[n] = __expf(x[n] - mx); sum += p[n]; }
    sum += __shfl_xor(sum, 1);
    sum += __shfl_xor(sum, 2);
    sum += __shfl_xor(sum, 4);
    sum += __shfl_xor(sum, 8);
    float inv = 1.0f / sum;
#pragma unroll
    for (int n = 0; n < 4; n++) p_s[row][n * 16 + lr] = f2bf(p[n] * inv);
    float sg = 1.0f / (1.0f + __expf(-accC[r4] * SCALE));
    crossv[r4] = __shfl(sg, (lane & 48));
  }
  __syncthreads();
  f32x4 accO[4];
#pragma unroll
  for (int n = 0; n < 4; n++) accO[n] = (f32x4){0.f, 0.f, 0.f, 0.f};
#pragma unroll
  for (int kt = 0; kt < 2; kt++) {
    int lk = kt * 32 + g * 8;
    short8 pf = *(const short8*)&p_s[w * 16 + lr][lk];
#pragma unroll
    for (int n = 0; n < 4; n++) {
      short8 vf = *(const short8*)&vt_s[n * 16 + lr][lk];
      accO[n] = __builtin_amdgcn_mfma_f32_16x16x32_bf16(pf, vf, accO[n], 0, 0, 0);
    }
  }
#pragma unroll
  for (int n = 0; n < 4; n++)
#pragma unroll
    for (int r4 = 0; r4 < 4; r4++) {
      int row = w * 16 + g * 4 + r4;
      int col = n * 16 + lr;
      float v = accO[n][r4] + crossv[r4] * cv_s[col] * 0.5f;
      out[(size_t)(row0 + row) * DIMC + h * 64 + col] = f2bf(v);
    }
}

extern "C" void kernel_launch(void* const* d_in, const int* in_sizes, int n_in,
                              void* d_out, int out_size, void* d_ws, size_t ws_size,
                              hipStream_t stream) {
  const float* x = (const float*)d_in[0];
  const float* Wqkv = (const float*)d_in[1];
  const float* Wout = (const float*)d_in[2];
  char* ws = (char*)d_ws;
  size_t off = 0;
  auto alloc = [&](size_t b) {
    void* p = ws + off;
    off += (b + 255) & ~(size_t)255;
    return p;
  };
  u16* xb = (u16*)alloc((size_t)NROWS * DIMC * 2);        // 32MB, reused as attnb
  u16* wqt = (u16*)alloc((size_t)QKVC * DIMC * 2);        // 6MB
  u16* wot = (u16*)alloc((size_t)DIMC * DIMC * 2);        // 2MB
  u16* qkvb = (u16*)alloc((size_t)NROWS * QKVC * 2);      // 96MB
  float* chk = (float*)alloc((size_t)4096 * 64 * 4);
  float* chv = (float*)alloc((size_t)4096 * 64 * 4);
  float* cuk = (float*)alloc((size_t)4096 * 64 * 4);
  float* cuv = (float*)alloc((size_t)4096 * 64 * 4);
  u16* attnb = xb;

  cvt_kernel<<<16384, 256, 0, stream>>>(x, xb, NROWS * DIMC / 4);
  transpose_cvt<<<3072, 256, 0, stream>>>(Wqkv, wqt, DIMC, QKVC);
  transpose_cvt<<<1024, 256, 0, stream>>>(Wout, wot, DIMC, DIMC);
  gemm_bt<1, 1><<<768, 512, 0, stream>>>(xb, wqt, qkvb, chk, chv, NROWS, QKVC, DIMC);
  cumsum_excl<<<64, 64, 0, stream>>>(chk, chv, cuk, cuv);
  attn_kernel<<<4096, 256, 0, stream>>>(qkvb, cuk, cuv, attnb);
  gemm_bt<0, 0><<<256, 512, 0, stream>>>(attnb, wot, d_out, nullptr, nullptr,
                                         NROWS, DIMC, DIMC);
}

// Round 9
// 206.382 us; speedup vs baseline: 1.1167x; 1.1157x over previous
//
#include <hip/hip_runtime.h>
#include <stdint.h>

typedef __attribute__((ext_vector_type(4))) float f32x4;
typedef __attribute__((ext_vector_type(8))) short short8;
typedef unsigned short u16;

#define NH 16
#define HD 64
#define SEQ 4096
#define BATCH 4
#define NROWS (BATCH * SEQ)      // 16384
#define DIMC 1024
#define QKVC 3072
#define SCALE 0.125f

__device__ __forceinline__ u16 f2bf(float f) {
  union { float f; uint32_t u; } v; v.f = f;
  uint32_t u = v.u;
  uint32_t r = (u + 0x7fffu + ((u >> 16) & 1u)) >> 16;
  return (u16)r;
}
__device__ __forceinline__ float bf2f(u16 h) {
  union { uint32_t u; float f; } v; v.u = ((uint32_t)h) << 16;
  return v.f;
}

// ---------------- fp32 -> bf16 elementwise convert (vectorized) ----------------
__global__ __launch_bounds__(256) void cvt_kernel(const float* __restrict__ in,
                                                  u16* __restrict__ out, int n4) {
  int i = blockIdx.x * 256 + threadIdx.x;
  if (i >= n4) return;
  float4 v = ((const float4*)in)[i];
  ushort4 o;
  o.x = f2bf(v.x); o.y = f2bf(v.y); o.z = f2bf(v.z); o.w = f2bf(v.w);
  ((ushort4*)out)[i] = o;
}

// ---------------- fp32 [R][C] -> bf16 [C][R] transpose ----------------
__global__ __launch_bounds__(256) void transpose_cvt(const float* __restrict__ in,
                                                     u16* __restrict__ out, int R, int C) {
  __shared__ float t[32][33];
  int nbx = C >> 5;
  int bx = blockIdx.x % nbx, by = blockIdx.x / nbx;
  int r0 = by << 5, c0 = bx << 5;
  int tid = threadIdx.x;
#pragma unroll
  for (int i = 0; i < 4; i++) {
    int id = i * 256 + tid; int lr = id >> 5, lc = id & 31;
    t[lr][lc] = in[(size_t)(r0 + lr) * C + (c0 + lc)];
  }
  __syncthreads();
#pragma unroll
  for (int i = 0; i < 4; i++) {
    int id = i * 256 + tid; int lr = id >> 5, lc = id & 31;
    out[(size_t)(c0 + lr) * R + (r0 + lc)] = f2bf(t[lc][lr]);
  }
}

// ---------------- bf16 GEMM: C[M,N] = A[M,K] * Bt[N,K]^T ----------------
// 8-phase m201 schedule, register-pressure-reduced:
//  - LDS flat [A0|A1|B0|B1] (16384 u16 each); ALL ds_reads = one of 4 base
//    VGPRs + compile-time offset immediate (buf/MH/m2 folded in, <64KB).
//  - quadrant order Q00,Q10,Q01,Q11: b0 live 2 phases, peak frag set 80 regs.
//  - staging: A(T+1) at P1/P2 (dest last-read prev tile P2); B(T+2) at P4
//    (b1 reads drained at P3's lgkm(0), one barrier before issue).
//  - vmcnt(4) at P4: outstanding = B(T+1),A(T+1),B(T+2) -> retires tile T+1.
// Budget: 2 waves/SIMD => 256 regs/wave total; acc=128 AGPR + ~112 arch.
template <int OUT_BF16, int DO_SUMS>
__global__ __launch_bounds__(512, 1) void gemm_bt(const u16* __restrict__ A,
                                                  const u16* __restrict__ Bt,
                                                  void* __restrict__ Cv,
                                                  float* __restrict__ chk,
                                                  float* __restrict__ chv,
                                                  int M, int N, int K) {
  __shared__ __align__(16) u16 lds[65536];  // A0|A1|B0|B1, 16384 u16 each
  int nbx = N >> 8;
  int nwg = gridDim.x;
  int bid = blockIdx.x;
  int cpx = nwg >> 3;                       // grids are multiples of 8
  int swz = (bid & 7) * cpx + (bid >> 3);
  int bx = swz % nbx, by = swz / nbx;
  int tid = threadIdx.x, lane = tid & 63, wv = tid >> 6;
  int wr = wv >> 2, wc = wv & 3;            // wave grid 2 (M) x 4 (N)
  int lr = lane & 15, g = lane >> 4;
  int rx = lr & 7;
  int rsub = lane >> 3;                     // staging: row within 8-row unit
  int clog = (lane & 7) ^ rsub;             // staging: logical (global) chunk

  const u16* Ap = A + (size_t)(by * 256) * K;
  const u16* Bp = Bt + (size_t)(bx * 256) * K;

  // 4 hoisted LDS read bases (lane-dependent swizzle folded in)
  const u16* aS0 = lds + (wr * 128 + lr) * 64 + ((g ^ rx) << 3);
  const u16* aS1 = lds + (wr * 128 + lr) * 64 + (((4 + g) ^ rx) << 3);
  const u16* bS0 = lds + 32768 + (wc * 64 + lr) * 64 + ((g ^ rx) << 3);
  const u16* bS1 = lds + 32768 + (wc * 64 + lr) * 64 + (((4 + g) ^ rx) << 3);

  f32x4 acc[8][4];
#pragma unroll
  for (int m = 0; m < 8; m++)
#pragma unroll
    for (int n = 0; n < 4; n++) acc[m][n] = (f32x4){0.f, 0.f, 0.f, 0.f};

  short8 a0[4][2], a1[4][2], b0[2][2], b1[2][2];

#define ISSUE_A(HALF, L, T, DBUF) do {                                          \
    int ru_ = (HALF) * 128 + (L) * 64 + wv * 8;                                 \
    const u16* g_ = Ap + (size_t)(ru_ + rsub) * K + (T) * 64 + clog * 8;        \
    __builtin_amdgcn_global_load_lds(                                           \
        (const __attribute__((address_space(1))) uint32_t*)g_,                  \
        (__attribute__((address_space(3)))                                      \
             uint32_t*)&lds[(DBUF) * 16384 + ru_ * 64],                         \
        16, 0, 0);                                                              \
  } while (0)

#define ISSUE_B(HALF, L, T, DBUF) do {                                          \
    int ru_ = (HALF) * 128 + (L) * 64 + wv * 8;                                 \
    const u16* g_ = Bp + (size_t)(ru_ + rsub) * K + (T) * 64 + clog * 8;        \
    __builtin_amdgcn_global_load_lds(                                           \
        (const __attribute__((address_space(1))) uint32_t*)g_,                  \
        (__attribute__((address_space(3)))                                      \
             uint32_t*)&lds[32768 + (DBUF) * 16384 + ru_ * 64],                 \
        16, 0, 0);                                                              \
  } while (0)

#define LDA(DST, MH, BUF) do {                                                  \
    _Pragma("unroll")                                                           \
    for (int m2 = 0; m2 < 4; m2++) {                                            \
      DST[m2][0] = *(const short8*)(aS0 + (BUF) * 16384 + (MH) * 4096 + m2 * 1024); \
      DST[m2][1] = *(const short8*)(aS1 + (BUF) * 16384 + (MH) * 4096 + m2 * 1024); \
    }                                                                           \
  } while (0)

#define LDB(DST, NHh, BUF) do {                                                 \
    _Pragma("unroll")                                                           \
    for (int n2 = 0; n2 < 2; n2++) {                                            \
      DST[n2][0] = *(const short8*)(bS0 + (BUF) * 16384 + (NHh) * 2048 + n2 * 1024); \
      DST[n2][1] = *(const short8*)(bS1 + (BUF) * 16384 + (NHh) * 2048 + n2 * 1024); \
    }                                                                           \
  } while (0)

#define MFMA_Q(MH, NHh, AA, BB) do {                                            \
    _Pragma("unroll")                                                           \
    for (int s = 0; s < 2; s++)                                                 \
      _Pragma("unroll")                                                         \
      for (int m2 = 0; m2 < 4; m2++)                                            \
        _Pragma("unroll")                                                       \
        for (int n2 = 0; n2 < 2; n2++)                                          \
          acc[(MH) * 4 + m2][(NHh) * 2 + n2] =                                  \
              __builtin_amdgcn_mfma_f32_16x16x32_bf16(                          \
                  AA[m2][s], BB[n2][s], acc[(MH) * 4 + m2][(NHh) * 2 + n2],     \
                  0, 0, 0);                                                     \
  } while (0)

#define PH_PRE(NREADS)                                                          \
    __builtin_amdgcn_sched_barrier(0);                                          \
    if ((NREADS) >= 12) { asm volatile("s_waitcnt lgkmcnt(8)" ::: "memory"); }  \
    __builtin_amdgcn_s_barrier();                                               \
    asm volatile("s_waitcnt lgkmcnt(0)" ::: "memory");                          \
    __builtin_amdgcn_sched_barrier(0);                                          \
    __builtin_amdgcn_s_setprio(1)

#define PH_POST                                                                 \
    __builtin_amdgcn_s_setprio(0);                                              \
    __builtin_amdgcn_sched_barrier(0);                                          \
    __builtin_amdgcn_s_barrier()

// One K-tile = 4 phases. Quadrants: Q00, Q10, Q01, Q11.
#define TILE_PHASES(BUF, T)                                                     \
    /* P1: rd a0,b0 | stage A(T+1) h0 | Q00 */                                  \
    LDA(a0, 0, BUF); LDB(b0, 0, BUF);                                           \
    if ((T) + 1 < NT) { ISSUE_A(0, 0, (T) + 1, (BUF) ^ 1);                      \
                        ISSUE_A(0, 1, (T) + 1, (BUF) ^ 1); }                    \
    PH_PRE(12);                                                                 \
    MFMA_Q(0, 0, a0, b0);                                                       \
    PH_POST;                                                                    \
    /* P2: rd a1 | stage A(T+1) h1 | Q10 */                                     \
    LDA(a1, 1, BUF);                                                            \
    if ((T) + 1 < NT) { ISSUE_A(1, 0, (T) + 1, (BUF) ^ 1);                      \
                        ISSUE_A(1, 1, (T) + 1, (BUF) ^ 1); }                    \
    PH_PRE(8);                                                                  \
    MFMA_Q(1, 0, a1, b0);                                                       \
    PH_POST;                                                                    \
    /* P3: rd b1 | Q01 */                                                       \
    LDB(b1, 1, BUF);                                                            \
    PH_PRE(4);                                                                  \
    MFMA_Q(0, 1, a0, b1);                                                       \
    PH_POST;                                                                    \
    /* P4: stage B(T+2) full | vmcnt(4) | Q11 */                                \
    if ((T) + 2 < NT) { ISSUE_B(0, 0, (T) + 2, BUF); ISSUE_B(0, 1, (T) + 2, BUF); \
                        ISSUE_B(1, 0, (T) + 2, BUF); ISSUE_B(1, 1, (T) + 2, BUF); } \
    __builtin_amdgcn_sched_barrier(0);                                          \
    if ((T) + 2 < NT) { asm volatile("s_waitcnt vmcnt(4)" ::: "memory"); }      \
    else              { asm volatile("s_waitcnt vmcnt(0)" ::: "memory"); }      \
    __builtin_amdgcn_sched_barrier(0);                                          \
    __builtin_amdgcn_s_barrier();                                               \
    __builtin_amdgcn_s_setprio(1);                                              \
    MFMA_Q(1, 1, a1, b1);                                                       \
    PH_POST

  int NT = K >> 6;
  // prologue: A(0), B(0), B(1); vmcnt(4) retires tile 0 exactly.
  ISSUE_A(0, 0, 0, 0); ISSUE_A(0, 1, 0, 0); ISSUE_A(1, 0, 0, 0); ISSUE_A(1, 1, 0, 0);
  ISSUE_B(0, 0, 0, 0); ISSUE_B(0, 1, 0, 0); ISSUE_B(1, 0, 0, 0); ISSUE_B(1, 1, 0, 0);
  ISSUE_B(0, 0, 1, 1); ISSUE_B(0, 1, 1, 1); ISSUE_B(1, 0, 1, 1); ISSUE_B(1, 1, 1, 1);
  __builtin_amdgcn_sched_barrier(0);
  asm volatile("s_waitcnt vmcnt(4)" ::: "memory");
  __builtin_amdgcn_sched_barrier(0);
  __builtin_amdgcn_s_barrier();

  int NI = NT >> 1;
  for (int i = 0; i < NI; i++) {
    int T0 = 2 * i, T1 = 2 * i + 1;
    TILE_PHASES(0, T0);
    TILE_PHASES(1, T1);
  }

#undef ISSUE_A
#undef ISSUE_B
#undef LDA
#undef LDB
#undef MFMA_Q
#undef PH_PRE
#undef PH_POST
#undef TILE_PHASES

  int rb = by * 256 + wr * 128, cb = bx * 256 + wc * 64;

  if (DO_SUMS && cb >= 1024) {
    // fused chunk means: wave owns chunks (wr*2+mh); sum fp32 acc over rows.
#pragma unroll
    for (int mh = 0; mh < 2; mh++)
#pragma unroll
      for (int n = 0; n < 4; n++) {
        float sum = 0.f;
#pragma unroll
        for (int m = mh * 4; m < mh * 4 + 4; m++)
#pragma unroll
          for (int r = 0; r < 4; r++) sum += acc[m][n][r];
        sum += __shfl_xor(sum, 16);
        sum += __shfl_xor(sum, 32);
        if (g == 0) {
          int grb = rb + mh * 64;
          int b = grb >> 12, c = (grb >> 6) & 63;
          int cg = cb + n * 16 + lr;
          int col = cg & 1023;
          int h = col >> 6, d = col & 63;
          float* dst = (cg < 2048) ? chk : chv;
          dst[(((size_t)(b * 16 + h)) * 64 + c) * 64 + d] = sum * 0.015625f;
        }
      }
  }

#pragma unroll
  for (int m = 0; m < 8; m++)
#pragma unroll
    for (int n = 0; n < 4; n++)
#pragma unroll
      for (int r = 0; r < 4; r++) {
        int rg = rb + m * 16 + g * 4 + r;
        int cg = cb + n * 16 + lr;
        float v = acc[m][n][r];
        if (OUT_BF16)
          ((u16*)Cv)[(size_t)rg * N + cg] = f2bf(v);
        else
          ((float*)Cv)[(size_t)rg * N + cg] = v;
      }
}

// ---------------- exclusive cumsum over chunks ----------------
__global__ void cumsum_excl(const float* __restrict__ ck, const float* __restrict__ cv,
                            float* __restrict__ cuk, float* __restrict__ cuv) {
  int bh = blockIdx.x;
  int d = threadIdx.x;
  float ak = 0.f, av = 0.f;
  for (int c = 0; c < 64; c++) {
    size_t i = ((size_t)bh * 64 + c) * 64 + d;
    cuk[i] = ak; cuv[i] = av;
    ak += ck[i]; av += cv[i];
  }
}

// ---------------- per-chunk attention + cross term ----------------
__global__ __launch_bounds__(256) void attn_kernel(const u16* __restrict__ qkv,
                                                   const float* __restrict__ cuk,
                                                   const float* __restrict__ cuv,
                                                   u16* __restrict__ out) {
  int blk = blockIdx.x;
  int c = blk & 63, h = (blk >> 6) & 15, b = blk >> 10;
  int row0 = b * SEQ + c * 64;
  __shared__ u16 q_s[64][80];
  __shared__ u16 k_s[64][80];
  __shared__ u16 vt_s[64][80];   // V transposed: vt_s[d][krow]
  __shared__ u16 p_s[64][80];
  __shared__ u16 ck_s[64];
  __shared__ float cv_s[64];
  int tid = threadIdx.x;
  {
    int r = tid >> 2, qt = tid & 3;
    const u16* rp = qkv + (size_t)(row0 + r) * QKVC + h * 64 + qt * 16;
    uint4 q0 = *(const uint4*)rp;          uint4 q1 = *(const uint4*)(rp + 8);
    uint4 k0 = *(const uint4*)(rp + 1024); uint4 k1 = *(const uint4*)(rp + 1032);
    uint4 v0 = *(const uint4*)(rp + 2048); uint4 v1 = *(const uint4*)(rp + 2056);
    *(uint4*)&q_s[r][qt * 16] = q0;     *(uint4*)&q_s[r][qt * 16 + 8] = q1;
    *(uint4*)&k_s[r][qt * 16] = k0;     *(uint4*)&k_s[r][qt * 16 + 8] = k1;
    const u16* vv0 = (const u16*)&v0;   const u16* vv1 = (const u16*)&v1;
#pragma unroll
    for (int j = 0; j < 8; j++) vt_s[qt * 16 + j][r] = vv0[j];
#pragma unroll
    for (int j = 0; j < 8; j++) vt_s[qt * 16 + 8 + j][r] = vv1[j];
    if (tid < 64) {
      ck_s[tid] = f2bf(cuk[(size_t)blk * 64 + tid]);
      cv_s[tid] = cuv[(size_t)blk * 64 + tid];
    }
  }
  __syncthreads();

  int lane = tid & 63, w = tid >> 6;
  int lr = lane & 15, g = lane >> 4;
  f32x4 accS[4];
#pragma unroll
  for (int n = 0; n < 4; n++) accS[n] = (f32x4){0.f, 0.f, 0.f, 0.f};
  f32x4 accC = (f32x4){0.f, 0.f, 0.f, 0.f};
  short8 zf = (short8){0, 0, 0, 0, 0, 0, 0, 0};
#pragma unroll
  for (int kt = 0; kt < 2; kt++) {
    int lk = kt * 32 + g * 8;
    short8 af = *(const short8*)&q_s[w * 16 + lr][lk];
    short8 cf = (lr == 0) ? *(const short8*)&ck_s[lk] : zf;
    accC = __builtin_amdgcn_mfma_f32_16x16x32_bf16(af, cf, accC, 0, 0, 0);
#pragma unroll
    for (int n = 0; n < 4; n++) {
      short8 bf = *(const short8*)&k_s[n * 16 + lr][lk];
      accS[n] = __builtin_amdgcn_mfma_f32_16x16x32_bf16(af, bf, accS[n], 0, 0, 0);
    }
  }
  float crossv[4];
#pragma unroll
  for (int r4 = 0; r4 < 4; r4++) {
    int row = w * 16 + g * 4 + r4;
    float x[4];
    float mx = -3.4e38f;
#pragma unroll
    for (int n = 0; n < 4; n++) {
      int col = n * 16 + lr;
      x[n] = ((col & 63) > (row & 63)) ? -65000.0f : accS[n][r4] * SCALE;
      mx = fmaxf(mx, x[n]);
    }
    mx = fmaxf(mx, __shfl_xor(mx, 1));
    mx = fmaxf(mx, __shfl_xor(mx, 2));
    mx = fmaxf(mx, __shfl_xor(mx, 4));
    mx = fmaxf(mx, __shfl_xor(mx, 8));
    float p[4], sum = 0.f;
#pragma unroll
    for (int n = 0; n < 4; n++) { p[n] = __expf(x[n] - mx); sum += p[n]; }
    sum += __shfl_xor(sum, 1);
    sum += __shfl_xor(sum, 2);
    sum += __shfl_xor(sum, 4);
    sum += __shfl_xor(sum, 8);
    float inv = 1.0f / sum;
#pragma unroll
    for (int n = 0; n < 4; n++) p_s[row][n * 16 + lr] = f2bf(p[n] * inv);
    float sg = 1.0f / (1.0f + __expf(-accC[r4] * SCALE));
    crossv[r4] = __shfl(sg, (lane & 48));
  }
  __syncthreads();
  f32x4 accO[4];
#pragma unroll
  for (int n = 0; n < 4; n++) accO[n] = (f32x4){0.f, 0.f, 0.f, 0.f};
#pragma unroll
  for (int kt = 0; kt < 2; kt++) {
    int lk = kt * 32 + g * 8;
    short8 pf = *(const short8*)&p_s[w * 16 + lr][lk];
#pragma unroll
    for (int n = 0; n < 4; n++) {
      short8 vf = *(const short8*)&vt_s[n * 16 + lr][lk];
      accO[n] = __builtin_amdgcn_mfma_f32_16x16x32_bf16(pf, vf, accO[n], 0, 0, 0);
    }
  }
#pragma unroll
  for (int n = 0; n < 4; n++)
#pragma unroll
    for (int r4 = 0; r4 < 4; r4++) {
      int row = w * 16 + g * 4 + r4;
      int col = n * 16 + lr;
      float v = accO[n][r4] + crossv[r4] * cv_s[col] * 0.5f;
      out[(size_t)(row0 + row) * DIMC + h * 64 + col] = f2bf(v);
    }
}

extern "C" void kernel_launch(void* const* d_in, const int* in_sizes, int n_in,
                              void* d_out, int out_size, void* d_ws, size_t ws_size,
                              hipStream_t stream) {
  const float* x = (const float*)d_in[0];
  const float* Wqkv = (const float*)d_in[1];
  const float* Wout = (const float*)d_in[2];
  char* ws = (char*)d_ws;
  size_t off = 0;
  auto alloc = [&](size_t b) {
    void* p = ws + off;
    off += (b + 255) & ~(size_t)255;
    return p;
  };
  u16* xb = (u16*)alloc((size_t)NROWS * DIMC * 2);        // 32MB, reused as attnb
  u16* wqt = (u16*)alloc((size_t)QKVC * DIMC * 2);        // 6MB
  u16* wot = (u16*)alloc((size_t)DIMC * DIMC * 2);        // 2MB
  u16* qkvb = (u16*)alloc((size_t)NROWS * QKVC * 2);      // 96MB
  float* chk = (float*)alloc((size_t)4096 * 64 * 4);
  float* chv = (float*)alloc((size_t)4096 * 64 * 4);
  float* cuk = (float*)alloc((size_t)4096 * 64 * 4);
  float* cuv = (float*)alloc((size_t)4096 * 64 * 4);
  u16* attnb = xb;

  cvt_kernel<<<16384, 256, 0, stream>>>(x, xb, NROWS * DIMC / 4);
  transpose_cvt<<<3072, 256, 0, stream>>>(Wqkv, wqt, DIMC, QKVC);
  transpose_cvt<<<1024, 256, 0, stream>>>(Wout, wot, DIMC, DIMC);
  gemm_bt<1, 1><<<768, 512, 0, stream>>>(xb, wqt, qkvb, chk, chv, NROWS, QKVC, DIMC);
  cumsum_excl<<<64, 64, 0, stream>>>(chk, chv, cuk, cuv);
  attn_kernel<<<4096, 256, 0, stream>>>(qkvb, cuk, cuv, attnb);
  gemm_bt<0, 0><<<256, 512, 0, stream>>>(attnb, wot, d_out, nullptr, nullptr,
                                         NROWS, DIMC, DIMC);
}